// Round 7
// baseline (199.853 us; speedup 1.0000x reference)
//
#include <hip/hip_runtime.h>
#include <stdint.h>

// RelScaleAttend: b=4, 16 heads, s=1024 (32x32 img), d=64. TWO kernels.
//
// K1 repack: K,V f32 -> bf16 in d_ws, in EXACT per-lane MFMA fragment order.
//   Per (head bh, 32-key tile kt32): 8 KB = 8 chunks x 1 KB:
//     chunks 0..3 : K QK-fragments, chunk g*2+ch: lane l holds
//                   K[key = kt32*32 + g*16 + (l&15)][dim = ch*32 + (l>>4)*8 + j]
//     chunks 4..7 : V PV-fragments, chunk 4+cn: lane l holds
//                   V[key = kt32*32 + (j>>2)*16 + (l>>4)*4 + (j&3)][dim = cn*16 + (l&15)]
//   So in attn, global_load_dwordx4 at chunk*1024 + lane*16 IS the fragment.
//
// K2 attn: ZERO barriers / ZERO LDS traffic in the main loop. Rounds 0-6
//   established time is invariant to phases, work, residency and access
//   pattern (~115-135us, all pipes <30%) -- the one shared element was
//   cross-wave LDS tiling with per-iteration barriers. Here each wave runs
//   free: 8 coalesced loads/tile straight into MFMA operands (4 waves issue
//   identical addresses -> L1 broadcast; head-tiles L2-resident via XCD
//   swizzle), register double-buffer (A/B sets, static indexing), no
//   vmcnt(0) drains ever (no barriers to force them). Swapped-operand QK^T
//   (lane holds full query rows), per-lane STATIC-max softmax (exact),
//   PV A-fragment = lane's own p values. Numerics identical to R0-R6.

#define SCALE2 0.18033688f   // 0.125 * log2(e)
#define LOG2E  1.44269504f

typedef float  f32x4  __attribute__((ext_vector_type(4)));
typedef __bf16 bf16x8 __attribute__((ext_vector_type(8)));

__device__ inline bf16x8 pack8(f32x4 a, f32x4 b) {
    bf16x8 t;
    t[0]=(__bf16)a.x; t[1]=(__bf16)a.y; t[2]=(__bf16)a.z; t[3]=(__bf16)a.w;
    t[4]=(__bf16)b.x; t[5]=(__bf16)b.y; t[6]=(__bf16)b.z; t[7]=(__bf16)b.w;
    return t;
}

// ---------------- kernel 1: repack into fragment order ----------------
__global__ __launch_bounds__(256) void repack(
        const float* __restrict__ kg, const float* __restrict__ vg,
        char* __restrict__ pk) {
    __shared__ float Kt[64 * 68];
    __shared__ float Vt[64 * 68];
    const int t   = threadIdx.x;
    const int idx = blockIdx.x;            // 1024 = 64 bh x 16 kt64
    const int bh  = idx >> 4, kt = idx & 15;
    const int bb  = bh >> 4, nh = bh & 15;
    const int inbase = bb * 1048576 + nh * 64;
    char* out = pk + bh * 262144 + kt * 16384;   // two 8KB kt32 tiles

    const int r  = t >> 2;                 // 0..63
    const int c0 = (t & 3) << 4;           // 0,16,32,48
    {
        const float* srck = kg + inbase + (kt * 64 + r) * 1024 + c0;
        const float* srcv = vg + inbase + (kt * 64 + r) * 1024 + c0;
#pragma unroll
        for (int i = 0; i < 4; ++i) {
            ((f32x4*)&Kt[r * 68 + c0])[i] = ((const f32x4*)srck)[i];
            ((f32x4*)&Vt[r * 68 + c0])[i] = ((const f32x4*)srcv)[i];
        }
    }
    __syncthreads();

    const int w = t >> 6, l = t & 63;
    const int n16 = l & 15, quad = l >> 4;

    // K fragment chunks: q = sub*4 + g*2 + ch; wave w does q = w, w+4
#pragma unroll
    for (int i = 0; i < 2; ++i) {
        int q = w + i * 4;
        int sub = q >> 2, g = (q >> 1) & 1, ch = q & 1;
        const float* src = &Kt[(sub * 32 + g * 16 + n16) * 68 + ch * 32 + quad * 8];
        f32x4 a = ((const f32x4*)src)[0], b = ((const f32x4*)src)[1];
        *(bf16x8*)(out + sub * 8192 + (g * 2 + ch) * 1024 + l * 16) = pack8(a, b);
    }
    // V fragment chunks: cq = sub*4 + cn; wave w does cq = w*2, w*2+1
#pragma unroll
    for (int i = 0; i < 2; ++i) {
        int cq = w * 2 + i;
        int sub = cq >> 2, cn = cq & 3;
        int dim = cn * 16 + n16;
        float x[8];
#pragma unroll
        for (int j = 0; j < 8; ++j)
            x[j] = Vt[(sub * 32 + (j >> 2) * 16 + quad * 4 + (j & 3)) * 68 + dim];
        f32x4 a = {x[0], x[1], x[2], x[3]}, b = {x[4], x[5], x[6], x[7]};
        *(bf16x8*)(out + sub * 8192 + 4096 + cn * 1024 + l * 16) = pack8(a, b);
    }
}

// ---------------- kernel 2: attention (barrier-free main loop) ----------------
__global__ __launch_bounds__(256, 3) void attn(
        const float* __restrict__ qg, const char* __restrict__ pk,
        const float* __restrict__ rph, const float* __restrict__ rpw,
        float* __restrict__ outg) {
    __shared__ float RelH[64 * 33];               // stride 33: conflict-free scalar reads
    __shared__ __align__(16) char arena[27136];   // phase-0 only
    float* Ql   = (float*)arena;                  // [0,17408)
    float* RelW = (float*)(arena + 17408);        // [17408,26112), stride 34
    float* MH   = (float*)(arena + 26112);        // [26112,27136)

    const int tid  = threadIdx.x;
    const int w    = tid >> 6, lane = tid & 63;
    const int quad = lane >> 4, n16 = lane & 15;

    // ---- XCD head-affinity swizzle ----
    const int idx = blockIdx.x;
    const int xc  = idx & 7;
    const int r_  = idx >> 3;
    const int hp  = r_ & 15;
    const int bh  = xc + ((r_ >> 4) << 3);

    const int bb = bh >> 4, nh = bh & 15;
    const int h0 = hp << 1;
    const int base = bb * 1048576 + nh * 64;      // per-head f32 element base
    const int sq0  = h0 * 32;                     // first query row of block
    const char* pkb = pk + bh * 262144;           // packed fragments for this head

    // ---- stage Q rows (fp32) into LDS, coalesced b128 ----
    {
        int r0 = tid >> 4, c0 = (tid & 15) << 2;
#pragma unroll
        for (int k = 0; k < 4; ++k) {
            int row = k * 16 + r0;
            f32x4 v = *(const f32x4*)(qg + base + (sq0 + row) * 1024 + c0);
            *(f32x4*)&Ql[row * 68 + c0] = v;
        }
    }
    __syncthreads();

    // ---- phase 0: rel tables (x log2e) + per-slot max ----
    {
        int ql = tid & 63, slot = tid >> 6;
        int isw = slot >> 1, khb = (slot & 1) << 4;
        int hh = h0 + (ql >> 5), wl = ql & 31;
        int row0 = (isw ? wl : hh) + 31 - khb;      // row_j = row0 - j
        const float* tp = (isw ? rpw : rph) + row0 * 64;
        const float* qrow = &Ql[ql * 68];
        float acc[16];
#pragma unroll
        for (int j = 0; j < 16; ++j) acc[j] = 0.f;
#pragma unroll 4
        for (int cq = 0; cq < 16; ++cq) {
            f32x4 qv = *(const f32x4*)(qrow + cq * 4);
#pragma unroll
            for (int j = 0; j < 16; ++j) {
                f32x4 tv = *(const f32x4*)(tp - j * 64 + cq * 4);
                acc[j] += qv.x * tv.x + qv.y * tv.y + qv.z * tv.z + qv.w * tv.w;
            }
        }
        float* dst = (isw ? RelW + ql * 34 : RelH + ql * 33) + khb;
        float hmax = -1e30f;
#pragma unroll
        for (int j = 0; j < 16; ++j) {
            float v = acc[j] * LOG2E;
            dst[j] = v;
            hmax = fmaxf(hmax, v);
        }
        MH[slot * 64 + ql] = hmax;
    }

    // ---- Q fragments (MFMA B-operand): lane holds Q[w*16+n16][quad*8+j]
    const int qn = w * 16 + n16;             // this lane's softmax query
    bf16x8 qf[2];
#pragma unroll
    for (int ch = 0; ch < 2; ++ch) {
        const float* qp = &Ql[qn * 68 + ch * 32 + quad * 8];
        f32x4 a = ((const f32x4*)qp)[0];
        f32x4 b = ((const f32x4*)qp)[1];
        qf[ch] = pack8(a, b);
    }
    __syncthreads();   // phase-0 writes visible everywhere; last barrier.

    // ---- per-lane static max M and rwm2[g][r] = RelW[qn][g*16+quad*4+r] - M
    float rwm2[2][4];
    {
        float M = fmaxf(MH[qn], MH[64 + qn]) + fmaxf(MH[128 + qn], MH[192 + qn]);
#pragma unroll
        for (int g = 0; g < 2; ++g) {
            float2 u  = *(const float2*)&RelW[qn * 34 + g * 16 + quad * 4];
            float2 v2 = *(const float2*)&RelW[qn * 34 + g * 16 + quad * 4 + 2];
            rwm2[g][0] = u.x - M;  rwm2[g][1] = u.y - M;
            rwm2[g][2] = v2.x - M; rwm2[g][3] = v2.y - M;
        }
    }

    float lr = 0.f;
    f32x4 oc[4];
#pragma unroll
    for (int i = 0; i < 4; ++i) oc[i] = (f32x4){0.f, 0.f, 0.f, 0.f};

    const char* lbase = pkb + lane * 16;
    const float* relhq = &RelH[qn * 33];

    // ---- load one 32-key tile's fragments straight into operand registers ----
#define LOADT(KF, VF, KT) do {                                          \
        const char* tb_ = lbase + (KT) * 8192;                          \
        _Pragma("unroll")                                               \
        for (int i_ = 0; i_ < 4; ++i_) {                                \
            KF[i_] = *(const bf16x8*)(tb_ + i_ * 1024);                 \
            VF[i_] = *(const bf16x8*)(tb_ + 4096 + i_ * 1024);          \
        }                                                               \
    } while (0)

    // ---- compute one 32-key tile: 8 MFMAs + per-lane softmax ----
#define COMPUTE(KF, VF, KT) do {                                        \
        float rh_ = relhq[(KT)];                                        \
        f32x4 s0_ = (f32x4){0.f,0.f,0.f,0.f};                           \
        f32x4 s1_ = (f32x4){0.f,0.f,0.f,0.f};                           \
        s0_ = __builtin_amdgcn_mfma_f32_16x16x32_bf16(KF[0], qf[0], s0_, 0,0,0); \
        s0_ = __builtin_amdgcn_mfma_f32_16x16x32_bf16(KF[1], qf[1], s0_, 0,0,0); \
        s1_ = __builtin_amdgcn_mfma_f32_16x16x32_bf16(KF[2], qf[0], s1_, 0,0,0); \
        s1_ = __builtin_amdgcn_mfma_f32_16x16x32_bf16(KF[3], qf[1], s1_, 0,0,0); \
        float p_[8];                                                    \
        _Pragma("unroll")                                               \
        for (int r_ = 0; r_ < 4; ++r_) {                                \
            p_[r_]     = __builtin_amdgcn_exp2f(fmaf(s0_[r_], SCALE2, rh_ + rwm2[0][r_])); \
            p_[4 + r_] = __builtin_amdgcn_exp2f(fmaf(s1_[r_], SCALE2, rh_ + rwm2[1][r_])); \
        }                                                               \
        lr += ((p_[0] + p_[1]) + (p_[2] + p_[3]))                       \
            + ((p_[4] + p_[5]) + (p_[6] + p_[7]));                      \
        bf16x8 pf_;                                                     \
        _Pragma("unroll")                                               \
        for (int j_ = 0; j_ < 8; ++j_) pf_[j_] = (__bf16)p_[j_];        \
        _Pragma("unroll")                                               \
        for (int cn_ = 0; cn_ < 4; ++cn_)                               \
            oc[cn_] = __builtin_amdgcn_mfma_f32_16x16x32_bf16(pf_, VF[cn_], oc[cn_], 0,0,0); \
    } while (0)

    bf16x8 kA[4], vA[4], kB[4], vB[4];
    LOADT(kA, vA, 0);
    for (int kt = 0; kt < 32; kt += 2) {
        LOADT(kB, vB, kt + 1);
        COMPUTE(kA, vA, kt);
        if (kt + 2 < 32) LOADT(kA, vA, kt + 2);
        COMPUTE(kB, vB, kt + 1);
    }
#undef LOADT
#undef COMPUTE

    // ---- epilogue: full row-sum per query, redistribute, store ----
    lr += __shfl_xor(lr, 16);
    lr += __shfl_xor(lr, 32);
    float linv[4];
#pragma unroll
    for (int r = 0; r < 4; ++r)
        linv[r] = 1.f / __shfl(lr, quad * 4 + r, 64);   // L[query = quad*4+r]

    // oc[cn][r] = O[query = w*16 + quad*4 + r][dim = cn*16 + n16]
#pragma unroll
    for (int r = 0; r < 4; ++r) {
        int ob = base + (sq0 + w * 16 + quad * 4 + r) * 1024 + n16;
        outg[ob]      = oc[0][r] * linv[r];
        outg[ob + 16] = oc[1][r] * linv[r];
        outg[ob + 32] = oc[2][r] * linv[r];
        outg[ob + 48] = oc[3][r] * linv[r];
    }
}

extern "C" void kernel_launch(void* const* d_in, const int* in_sizes, int n_in,
                              void* d_out, int out_size, void* d_ws, size_t ws_size,
                              hipStream_t stream) {
    (void)in_sizes; (void)n_in; (void)out_size; (void)ws_size;
    const float* q   = (const float*)d_in[0];
    const float* k   = (const float*)d_in[1];
    const float* v   = (const float*)d_in[2];
    const float* rph = (const float*)d_in[3];
    const float* rpw = (const float*)d_in[4];
    char* pk = (char*)d_ws;                 // 16 MB packed K/V fragments
    repack<<<dim3(1024), 256, 0, stream>>>(k, v, pk);
    attn<<<dim3(1024), 256, 0, stream>>>(q, pk, rph, rpw, (float*)d_out);
}

// Round 9
// 146.471 us; speedup vs baseline: 1.3645x; 1.3645x over previous
//
#include <hip/hip_runtime.h>
#include <stdint.h>

// RelScaleAttend: b=4, 16 heads, s=1024 (32x32 img), d=64. TWO kernels.
//
// K1 repack (unchanged from R6): K,V f32 -> bf16 tiles in d_ws, 8 KB per
//   (head, 64-key tile): Kp[row][dim] and Vp[dim][key] (transposed), both with
//   the LDS XOR swizzle (byte ^= (row&7)<<4) pre-baked.
//
// K2 attn: R6's main loop kept BYTE-IDENTICAL (gl_lds staging, double buffer,
//   one wait+barrier per 64-key tile) -- only PHASE 0 is rewritten. R0-R7
//   established (~115-135us, all pipes <30%) that time is invariant to loop
//   structure; the untouched invariant was phase 0, whose rel-table loads are
//   per-lane SCATTERED (RelW waves: 32 distinct 16B segments per instruction
//   => ~32 line-probes/inst x 256 insts/wave of address-path serialization).
//   New phase 0: T[q][j] = dot(Q[q], tbl[j]) with WAVE-UNIFORM table addresses
//   (readfirstlane base -> scalar-cache loads, 1 line/inst), lane = row q,
//   24 columns/wave (33 H + 63 W = 96). Values stored straight into consumer
//   layout: ThS[q][kh] (R6's swizzled RelH layout; main-loop read unchanged),
//   TwS[q][kw] with kh=(q>>5)+31-j, kw=(q&31)+31-j. Exact fp32, same numerics.
//
// LDS 40960 B -> 4 blocks/CU: ThS 8192 | arena 32768:
//   phase0: Ql [0,17408) | TwS stride-36 [17408,26624)
//   main:   buf0 [0,16384) | buf1 [16384,32768)
//   (Ql dead before buf0's first write; TwS consumed into registers before the
//    iter-0 barrier, which waits lgkmcnt(0) -- closes the buf1/TwS race.)

#define SCALE2 0.18033688f   // 0.125 * log2(e)
#define LOG2E  1.44269504f

typedef float  f32x4  __attribute__((ext_vector_type(4)));
typedef __bf16 bf16x8 __attribute__((ext_vector_type(8)));
typedef __bf16 bf16x4 __attribute__((ext_vector_type(4)));

#define AS1 __attribute__((address_space(1)))
#define AS3 __attribute__((address_space(3)))

__device__ inline bf16x8 pack8(f32x4 a, f32x4 b) {
    bf16x8 t;
    t[0]=(__bf16)a.x; t[1]=(__bf16)a.y; t[2]=(__bf16)a.z; t[3]=(__bf16)a.w;
    t[4]=(__bf16)b.x; t[5]=(__bf16)b.y; t[6]=(__bf16)b.z; t[7]=(__bf16)b.w;
    return t;
}

// ---------------- kernel 1: repack (verbatim R6) ----------------
__global__ __launch_bounds__(256) void repack(
        const float* __restrict__ kg, const float* __restrict__ vg,
        char* __restrict__ kp, char* __restrict__ vp) {
    __shared__ float Vt[64 * 68];
    const int t   = threadIdx.x;
    const int idx = blockIdx.x;            // 1024 = 64 bh x 16 kt
    const int bh  = idx >> 4, kt = idx & 15;
    const int bb  = bh >> 4, nh = bh & 15;
    const int inbase = bb * 1048576 + nh * 64;
    char* kout = kp + bh * 131072 + kt * 8192;
    char* vout = vp + bh * 131072 + kt * 8192;

    const int r  = t >> 2;                 // 0..63
    const int c0 = (t & 3) << 4;           // 0,16,32,48

    {   // K: row r, 16 dims -> swizzled bf16
        const float* src = kg + inbase + (kt * 64 + r) * 1024 + c0;
        f32x4 a = ((const f32x4*)src)[0], b = ((const f32x4*)src)[1];
        f32x4 c = ((const f32x4*)src)[2], d = ((const f32x4*)src)[3];
        const int swz = (r & 7) << 4;
        *(bf16x8*)(kout + r * 128 + ((c0 * 2) ^ swz))      = pack8(a, b);
        *(bf16x8*)(kout + r * 128 + ((c0 * 2 + 16) ^ swz)) = pack8(c, d);
    }
    {   // V rows -> LDS
        const float* src = vg + inbase + (kt * 64 + r) * 1024 + c0;
        f32x4 a = ((const f32x4*)src)[0], b = ((const f32x4*)src)[1];
        f32x4 c = ((const f32x4*)src)[2], d = ((const f32x4*)src)[3];
        float* dst = &Vt[r * 68 + c0];
        ((f32x4*)dst)[0] = a; ((f32x4*)dst)[1] = b;
        ((f32x4*)dst)[2] = c; ((f32x4*)dst)[3] = d;
    }
    __syncthreads();
    {   // transpose -> [dim][key] swizzled bf16
        const int d0  = r;
        const int kk0 = c0;
        float x[16];
#pragma unroll
        for (int j = 0; j < 16; ++j) x[j] = Vt[(kk0 + j) * 68 + d0];
        f32x4 a = {x[0], x[1], x[2], x[3]},   b = {x[4], x[5], x[6], x[7]};
        f32x4 c = {x[8], x[9], x[10], x[11]}, d = {x[12], x[13], x[14], x[15]};
        const int swz = (d0 & 7) << 4;
        *(bf16x8*)(vout + d0 * 128 + ((kk0 * 2) ^ swz))      = pack8(a, b);
        *(bf16x8*)(vout + d0 * 128 + ((kk0 * 2 + 16) ^ swz)) = pack8(c, d);
    }
}

// ---------------- kernel 2: attention ----------------
__global__ __launch_bounds__(256, 4) void attn(
        const float* __restrict__ qg,
        const char* __restrict__ kp, const char* __restrict__ vp,
        const float* __restrict__ rph, const float* __restrict__ rpw,
        float* __restrict__ outg) {
    __shared__ float ThS[64 * 32];                // 8192 B, swizzled rows (= R6 RelH)
    __shared__ __align__(16) char arena[32768];
    float* Ql  = (float*)arena;                   // phase0 [0,17408)
    float* TwS = (float*)(arena + 17408);         // phase0 [17408,26624), stride 36

    const int tid  = threadIdx.x;
    const int w    = tid >> 6, lane = tid & 63;
    const int quad = lane >> 4, n16 = lane & 15;
    const int sw16 = (n16 & 7) << 4;              // read-side row swizzle

    // ---- XCD head-affinity swizzle ----
    const int idx = blockIdx.x;
    const int xc  = idx & 7;
    const int r_  = idx >> 3;
    const int hp  = r_ & 15;
    const int bh  = xc + ((r_ >> 4) << 3);

    const int bb = bh >> 4, nh = bh & 15;
    const int h0 = hp << 1;
    const int base = bb * 1048576 + nh * 64;      // per-head f32 element base
    const int sq0  = h0 * 32;                     // first query row of block
    const char* kpb = kp + bh * 131072;
    const char* vpb = vp + bh * 131072;

    // ---- stage Q rows (fp32) into LDS, coalesced b128 ----
    {
        int r0 = tid >> 4, c0 = (tid & 15) << 2;
#pragma unroll
        for (int k = 0; k < 4; ++k) {
            int row = k * 16 + r0;
            f32x4 v = *(const f32x4*)(qg + base + (sq0 + row) * 1024 + c0);
            *(f32x4*)&Ql[row * 68 + c0] = v;
        }
    }
    __syncthreads();

    // ---- phase 0 (NEW): T[q][j] = dot(Q[q], tbl[j]) with uniform tbl addrs ----
    // 96 columns total: cid 0..32 -> rph row h0+cid; cid 33..95 -> rpw row cid-33.
    // wave wu owns cid = wu*24 .. wu*24+23; lane owns q = lane.
    {
        const int wu = __builtin_amdgcn_readfirstlane(w);
        const float* qrow = &Ql[lane * 68];
        const float* hb = rph + h0 * 64;          // + cid*64
        const float* wb = rpw - 33 * 64;          // + cid*64
        float acc[24];
#pragma unroll
        for (int i = 0; i < 24; ++i) acc[i] = 0.f;
        for (int cq = 0; cq < 16; ++cq) {
            f32x4 qv = *(const f32x4*)(qrow + cq * 4);
#pragma unroll
            for (int i = 0; i < 24; ++i) {
                int cid = wu * 24 + i;
                const float* tb = (cid < 33 ? hb : wb) + cid * 64;
                f32x4 tv = *(const f32x4*)(tb + cq * 4);   // wave-uniform addr
                acc[i] += qv.x * tv.x + qv.y * tv.y + qv.z * tv.z + qv.w * tv.w;
            }
        }
        // store in consumer layout (x log2e). Row = lane.
#pragma unroll
        for (int i = 0; i < 24; ++i) {
            int cid = wu * 24 + i;
            float v = acc[i] * LOG2E;
            if (cid < 33) {
                int kh = (lane >> 5) + 31 - cid;          // j-local = cid
                if (kh >= 0 && kh < 32)
                    *(float*)((char*)ThS + lane * 128 + ((kh * 4) ^ ((lane & 7) << 4))) = v;
            } else {
                int kw = (lane & 31) + 31 - (cid - 33);
                if (kw >= 0 && kw < 32)
                    TwS[lane * 36 + kw] = v;
            }
        }
    }

    // ---- Q fragments (MFMA B-operand): lane holds Q[w*16+n16][quad*8+j]
    const int qn = w * 16 + n16;             // this lane's softmax query
    bf16x8 qf[2];
#pragma unroll
    for (int ch = 0; ch < 2; ++ch) {
        const float* qp = &Ql[qn * 68 + ch * 32 + quad * 8];
        f32x4 a = ((const f32x4*)qp)[0];
        f32x4 b = ((const f32x4*)qp)[1];
        qf[ch] = pack8(a, b);
    }
    __syncthreads();   // phase-0 writes visible; Ql reads done everywhere

    // ---- per-lane static max M and rwm2[g][r] = rel_w[qn][g*16+quad*4+r] - M
    float rwm2[2][4];
    {
        float mh = -1e30f, mw = -1e30f;
#pragma unroll
        for (int i = 0; i < 8; ++i) {
            f32x4 a = *(const f32x4*)((const char*)ThS + qn * 128 + ((i * 16) ^ sw16));
            f32x4 b = *(const f32x4*)&TwS[qn * 36 + i * 4];
            mh = fmaxf(mh, fmaxf(fmaxf(a.x, a.y), fmaxf(a.z, a.w)));
            mw = fmaxf(mw, fmaxf(fmaxf(b.x, b.y), fmaxf(b.z, b.w)));
        }
        float M = mh + mw;
#pragma unroll
        for (int g = 0; g < 2; ++g)
#pragma unroll
            for (int r = 0; r < 4; ++r)
                rwm2[g][r] = TwS[qn * 36 + g * 16 + quad * 4 + r] - M;
    }

    float lr = 0.f;
    f32x4 oc[4];
#pragma unroll
    for (int i = 0; i < 4; ++i) oc[i] = (f32x4){0.f, 0.f, 0.f, 0.f};

    // ---- async staging (R6 verbatim): 4 gl_lds dwordx4 per thread per tile ----
    const int lo16 = lane * 16;
    auto GLDS = [&](int buf, int kt) {
        const char* ks = kpb + kt * 8192 + w * 2048 + lo16;
        const char* vs = vpb + kt * 8192 + w * 2048 + lo16;
        char* ld = arena + buf * 16384 + w * 2048;
        __builtin_amdgcn_global_load_lds((const AS1 void*)ks,
                                         (AS3 void*)ld,          16, 0, 0);
        __builtin_amdgcn_global_load_lds((const AS1 void*)(ks + 1024),
                                         (AS3 void*)(ld + 1024), 16, 0, 0);
        __builtin_amdgcn_global_load_lds((const AS1 void*)vs,
                                         (AS3 void*)(ld + 8192), 16, 0, 0);
        __builtin_amdgcn_global_load_lds((const AS1 void*)(vs + 1024),
                                         (AS3 void*)(ld + 9216), 16, 0, 0);
    };

    GLDS(0, 0);   // prologue: tile 0 -> buf0 (Ql region, dead)

    for (int kt = 0; kt < 16; ++kt) {
        // staging of buf[kt&1] done + all LDS ops (incl. TwS reads at kt=0)
        asm volatile("s_waitcnt vmcnt(0) lgkmcnt(0)" ::: "memory");
        __builtin_amdgcn_s_barrier();

        if (kt < 15) GLDS((kt + 1) & 1, kt + 1);

        const char* kbase = arena + (kt & 1) * 16384;
        const char* vbase = kbase + 8192;

        // ---- S^T = K Q^T : 8 MFMAs; s[g][r] = S[key=g*16+quad*4+r][qn] ----
        f32x4 s[4];
#pragma unroll
        for (int g = 0; g < 4; ++g) s[g] = (f32x4){0.f, 0.f, 0.f, 0.f};
#pragma unroll
        for (int ch = 0; ch < 2; ++ch)
#pragma unroll
            for (int g = 0; g < 4; ++g) {
                bf16x8 kf = *(const bf16x8*)(kbase + (g * 16 + n16) * 128
                                             + ((ch * 64 + quad * 16) ^ sw16));
                s[g] = __builtin_amdgcn_mfma_f32_16x16x32_bf16(kf, qf[ch], s[g], 0, 0, 0);
            }

        // ---- static-max softmax: kh=kt*2+(g>>1), kw=(g&1)*16+quad*4+r ----
        float2 rhp = *(const float2*)((const char*)ThS + qn * 128 + ((kt * 8) ^ sw16));
        float p[4][4];
#pragma unroll
        for (int g = 0; g < 4; ++g) {
            const float rbase = (g >= 2) ? rhp.y : rhp.x;
#pragma unroll
            for (int r = 0; r < 4; ++r)
                p[g][r] = __builtin_amdgcn_exp2f(fmaf(s[g][r], SCALE2, rbase + rwm2[g & 1][r]));
        }
#pragma unroll
        for (int g = 0; g < 4; ++g)
            lr += ((p[g][0] + p[g][1]) + (p[g][2] + p[g][3]));

        // ---- PV A-fragments: lane's own p values (zero shuffle) ----
        bf16x8 pf[2];
#pragma unroll
        for (int ko = 0; ko < 2; ++ko) {
            bf16x8 t;
            t[0] = (__bf16)p[2 * ko][0];     t[1] = (__bf16)p[2 * ko][1];
            t[2] = (__bf16)p[2 * ko][2];     t[3] = (__bf16)p[2 * ko][3];
            t[4] = (__bf16)p[2 * ko + 1][0]; t[5] = (__bf16)p[2 * ko + 1][1];
            t[6] = (__bf16)p[2 * ko + 1][2]; t[7] = (__bf16)p[2 * ko + 1][3];
            pf[ko] = t;
        }

        // ---- O += P V : B-fragment from packed [dim][key] swizzled V tile ----
#pragma unroll
        for (int ko = 0; ko < 2; ++ko)
#pragma unroll
            for (int cn = 0; cn < 4; ++cn) {
                const char* vb = vbase + (cn * 16 + n16) * 128;
                bf16x4 a = *(const bf16x4*)(vb + ((ko * 64 + quad * 8) ^ sw16));
                bf16x4 b = *(const bf16x4*)(vb + ((ko * 64 + quad * 8 + 32) ^ sw16));
                bf16x8 vf;
                vf[0] = a[0]; vf[1] = a[1]; vf[2] = a[2]; vf[3] = a[3];
                vf[4] = b[0]; vf[5] = b[1]; vf[6] = b[2]; vf[7] = b[3];
                oc[cn] = __builtin_amdgcn_mfma_f32_16x16x32_bf16(pf[ko], vf, oc[cn], 0, 0, 0);
            }
    }

    // ---- epilogue: full row-sum per query, redistribute, store ----
    lr += __shfl_xor(lr, 16);
    lr += __shfl_xor(lr, 32);
    float linv[4];
#pragma unroll
    for (int r = 0; r < 4; ++r)
        linv[r] = 1.f / __shfl(lr, quad * 4 + r, 64);   // L[query = quad*4+r]

    // oc[cn][r] = O[query = w*16 + quad*4 + r][dim = cn*16 + n16]
#pragma unroll
    for (int r = 0; r < 4; ++r) {
        int ob = base + (sq0 + w * 16 + quad * 4 + r) * 1024 + n16;
        outg[ob]      = oc[0][r] * linv[r];
        outg[ob + 16] = oc[1][r] * linv[r];
        outg[ob + 32] = oc[2][r] * linv[r];
        outg[ob + 48] = oc[3][r] * linv[r];
    }
}

extern "C" void kernel_launch(void* const* d_in, const int* in_sizes, int n_in,
                              void* d_out, int out_size, void* d_ws, size_t ws_size,
                              hipStream_t stream) {
    (void)in_sizes; (void)n_in; (void)out_size; (void)ws_size;
    const float* q   = (const float*)d_in[0];
    const float* k   = (const float*)d_in[1];
    const float* v   = (const float*)d_in[2];
    const float* rph = (const float*)d_in[3];
    const float* rpw = (const float*)d_in[4];
    char* kp = (char*)d_ws;                 // 8 MB packed K
    char* vp = kp + 8388608;                // 8 MB packed V
    repack<<<dim3(1024), 256, 0, stream>>>(k, v, kp, vp);
    attn<<<dim3(1024), 256, 0, stream>>>(q, kp, vp, rph, rpw, (float*)d_out);
}